// Round 6
// baseline (1464.661 us; speedup 1.0000x reference)
//
#include <hip/hip_runtime.h>
#include <hip/hip_cooperative_groups.h>

namespace cg = cooperative_groups;

#define D 128
#define NBLK 512    // 2 blocks/CU x 256 CUs -> co-resident with big margin at launch_bounds(256,2)
#define NTHR 256

typedef unsigned int uint;
typedef unsigned short ushort;
typedef __attribute__((ext_vector_type(8))) short bf16x8;
typedef __attribute__((ext_vector_type(4))) float f32x4;

// ---- bf16x2 pack/unpack (packed uint: low16 = even dim, high16 = odd dim) ----
__device__ __forceinline__ float2 bf2_to_f2(uint v) {
    union { uint u; float f; } a, b;
    a.u = v << 16;
    b.u = v & 0xffff0000u;
    return make_float2(a.f, b.f);
}
__device__ __forceinline__ uint f2_to_bf2(float x, float y) {
    uint xu = __float_as_uint(x), yu = __float_as_uint(y);
    xu += 0x7fffu + ((xu >> 16) & 1u);   // round-to-nearest-even
    yu += 0x7fffu + ((yu >> 16) & 1u);
    return (xu >> 16) | (yu & 0xffff0000u);
}

// one propagation hop: zout[c] = scale(c) * (zin[c] + sum_{in-nbrs r} zin[r])
__device__ __forceinline__ void prop_phase(const uint* zin, uint* zout,
                                           const int* offs, const int* srcs,
                                           const float* dinv, int mode, int n,
                                           int wgid, int nwav, int lane) {
    for (int c = wgid; c < n; c += nwav) {
        int beg = offs[c], end = offs[c + 1];
        size_t selfoff = (size_t)c * 64 + lane;
        float2 acc = bf2_to_f2(zin[selfoff]);     // self-loop term
        int k = beg;
        for (; k + 3 < end; k += 4) {             // 4 rows in flight per wave
            uint v0 = zin[(size_t)srcs[k]     * 64 + lane];
            uint v1 = zin[(size_t)srcs[k + 1] * 64 + lane];
            uint v2 = zin[(size_t)srcs[k + 2] * 64 + lane];
            uint v3 = zin[(size_t)srcs[k + 3] * 64 + lane];
            float2 f0 = bf2_to_f2(v0), f1 = bf2_to_f2(v1);
            float2 f2 = bf2_to_f2(v2), f3 = bf2_to_f2(v3);
            acc.x += (f0.x + f1.x) + (f2.x + f3.x);
            acc.y += (f0.y + f1.y) + (f2.y + f3.y);
        }
        for (; k < end; ++k) {
            float2 f = bf2_to_f2(zin[(size_t)srcs[k] * 64 + lane]);
            acc.x += f.x; acc.y += f.y;
        }
        float s = dinv[c];
        float sc = mode ? s : s * s;
        zout[selfoff] = f2_to_bf2(acc.x * sc, acc.y * sc);
    }
}

__global__ __launch_bounds__(NTHR, 2) void mega_kernel(
    const float* __restrict__ x, const int* __restrict__ ei,
    const float* __restrict__ W, const float* __restrict__ bias,
    float* __restrict__ out, int n, int E,
    int* __restrict__ deg8, int* __restrict__ offs, int* __restrict__ cursorc,
    int* __restrict__ srcs, float* __restrict__ dinv, int* __restrict__ partial,
    uint* __restrict__ zA, uint* __restrict__ zB, ushort* __restrict__ Wbf) {

    cg::grid_group grid = cg::this_grid();
    __shared__ int sh[NTHR];
    int t = threadIdx.x;
    int b = blockIdx.x;
    int gtid = b * NTHR + t;
    int gsize = NBLK * NTHR;
    int xcd = b & 7;
    int wv = t >> 6, lane = t & 63;
    int wgid = b * 4 + wv;
    int nwav = NBLK * 4;
    int nb = (n + 1023) >> 10;   // scan chunks (49 <= 64)

    // ---- P0: zero per-XCD degree tables ----
    for (int i = gtid; i < 8 * n; i += gsize) deg8[i] = 0;
    if (gtid == 0) offs[n] = E;
    __threadfence(); grid.sync(); __threadfence();

    // ---- P1: count in-degree, XCD-private copies ----
    {
        int* dgc = deg8 + xcd * n;
        for (int base = gtid * 4; base < E; base += gsize * 4) {
            if (base + 3 < E) {
                int4 c4 = *(const int4*)(ei + E + base);
                atomicAdd(&dgc[c4.x], 1); atomicAdd(&dgc[c4.y], 1);
                atomicAdd(&dgc[c4.z], 1); atomicAdd(&dgc[c4.w], 1);
            } else {
                for (int e = base; e < E; ++e) atomicAdd(&dgc[ei[E + e]], 1);
            }
        }
    }
    __threadfence(); grid.sync(); __threadfence();

    // ---- P2a: per-1024-node chunk partial sums ----
    for (int c = b; c < nb; c += NBLK) {
        int base = c * 1024 + t * 4;
        int s = 0;
#pragma unroll
        for (int jj = 0; jj < 4; ++jj) {
            int i = base + jj;
            if (i < n) {
#pragma unroll
                for (int j = 0; j < 8; ++j) s += deg8[j * n + i];
            }
        }
        sh[t] = s;
        __syncthreads();
        for (int off = 128; off > 0; off >>= 1) {
            if (t < off) sh[t] += sh[t + off];
            __syncthreads();
        }
        if (t == 0) partial[c] = sh[0];
        __syncthreads();
    }
    __threadfence(); grid.sync(); __threadfence();

    // ---- P2b: exclusive scan of chunk partials (block 0, one wave) ----
    if (b == 0 && t < 64) {
        int v = (t < nb) ? partial[t] : 0;
        int incl = v;
        for (int off = 1; off < 64; off <<= 1) {
            int o = __shfl_up(incl, off);
            if (t >= off) incl += o;
        }
        if (t < nb) partial[t] = incl - v;
    }
    __threadfence(); grid.sync(); __threadfence();

    // ---- P2c: local scan + apply: offs, dinv, 8 per-XCD cursor sub-ranges ----
    for (int c = b; c < nb; c += NBLK) {
        int base = c * 1024 + t * 4;
        int d[4][8], tot[4]; int s = 0;
#pragma unroll
        for (int jj = 0; jj < 4; ++jj) {
            int i = base + jj;
            tot[jj] = 0;
#pragma unroll
            for (int j = 0; j < 8; ++j) {
                d[jj][j] = (i < n) ? deg8[j * n + i] : 0;
                tot[jj] += d[jj][j];
            }
            s += tot[jj];
        }
        sh[t] = s;
        __syncthreads();
        int val = s;
        for (int off = 1; off < 256; off <<= 1) {
            int add = (t >= off) ? sh[t - off] : 0;
            __syncthreads();
            val += add; sh[t] = val;
            __syncthreads();
        }
        int run = val - s + partial[c];
#pragma unroll
        for (int jj = 0; jj < 4; ++jj) {
            int i = base + jj;
            if (i < n) {
                offs[i] = run;
                dinv[i] = rsqrtf((float)(tot[jj] + 1));   // +1 self-loop
                int sub = run;
#pragma unroll
                for (int j = 0; j < 8; ++j) { cursorc[j * n + i] = sub; sub += d[jj][j]; }
            }
            run += tot[jj];
        }
        __syncthreads();
    }
    __threadfence(); grid.sync(); __threadfence();

    // ---- P3: counting-sort edges by target (XCD-local cursors; same edge->block map as P1) ----
    {
        int* cur = cursorc + xcd * n;
        for (int base = gtid * 4; base < E; base += gsize * 4) {
            if (base + 3 < E) {
                int4 r4 = *(const int4*)(ei + base);
                int4 c4 = *(const int4*)(ei + E + base);
                srcs[atomicAdd(&cur[c4.x], 1)] = r4.x;
                srcs[atomicAdd(&cur[c4.y], 1)] = r4.y;
                srcs[atomicAdd(&cur[c4.z], 1)] = r4.z;
                srcs[atomicAdd(&cur[c4.w], 1)] = r4.w;
            } else {
                for (int e = base; e < E; ++e)
                    srcs[atomicAdd(&cur[ei[E + e]], 1)] = ei[e];
            }
        }
    }
    __threadfence(); grid.sync(); __threadfence();

    // ---- P4: z0 = bf16(dinv * x); W -> bf16 ----
    for (int i = gtid; i < n * 32; i += gsize) {   // float4 in, uint2 out
        int node = i >> 5;
        float4 v = ((const float4*)x)[i];
        float s = dinv[node];
        uint2 o;
        o.x = f2_to_bf2(v.x * s, v.y * s);
        o.y = f2_to_bf2(v.z * s, v.w * s);
        ((uint2*)zA)[i] = o;
    }
    for (int i = gtid; i < (D * D) / 2; i += gsize) {
        float2 wv2 = ((const float2*)W)[i];
        ((uint*)Wbf)[i] = f2_to_bf2(wv2.x, wv2.y);
    }
    __threadfence(); grid.sync(); __threadfence();

    // ---- P5: hop 1: zB = dinv^2 (A+I) zA ----
    prop_phase(zA, zB, offs, srcs, dinv, 0, n, wgid, nwav, lane);
    __threadfence(); grid.sync(); __threadfence();

    // ---- P6: hop 2: zA = dinv (A+I) zB ----
    prop_phase(zB, zA, offs, srcs, dinv, 1, n, wgid, nwav, lane);
    __threadfence(); grid.sync(); __threadfence();

    // ---- P7: out = relu(zA @ W^T + b), MFMA, LDS-free (A/B frags direct from global) ----
    {
        int mrow = lane & 15, quad = lane >> 4;
        int ntiles = (n + 15) >> 4;
        for (int tt = wgid; tt < ntiles; tt += nwav) {
            int m0 = tt * 16;
            int arow = m0 + mrow; if (arow >= n) arow = n - 1;
            const ushort* zrow = (const ushort*)zA + (size_t)arow * D;
            bf16x8 a[4];
#pragma unroll
            for (int q = 0; q < 4; ++q)
                a[q] = *(const bf16x8*)(zrow + q * 32 + quad * 8);   // A[m=lane&15][k]
            f32x4 acc[8];
#pragma unroll
            for (int ht = 0; ht < 8; ++ht) {
                acc[ht] = (f32x4){0.f, 0.f, 0.f, 0.f};
                const ushort* wrow = Wbf + (size_t)(ht * 16 + mrow) * D;  // B[k][n]=W[h=n][d=k]
#pragma unroll
                for (int q = 0; q < 4; ++q) {
                    bf16x8 bfr = *(const bf16x8*)(wrow + q * 32 + quad * 8);
                    acc[ht] = __builtin_amdgcn_mfma_f32_16x16x32_bf16(a[q], bfr, acc[ht], 0, 0, 0);
                }
            }
#pragma unroll
            for (int ht = 0; ht < 8; ++ht) {
                int h = ht * 16 + mrow;
                float bv = bias[h];
#pragma unroll
                for (int reg = 0; reg < 4; ++reg) {
                    int node = m0 + quad * 4 + reg;   // C/D: col=lane&15, row=quad*4+reg
                    if (node < n)
                        out[(size_t)node * D + h] = fmaxf(acc[ht][reg] + bv, 0.f);
                }
            }
        }
    }
}

// ================== fallback path: proven R4 multi-kernel sequence ==================

__global__ __launch_bounds__(256) void count_kernel(const int* __restrict__ ei, int E,
                                                    int* __restrict__ deg8, int N) {
    int j = blockIdx.x & 7;
    int* d = deg8 + j * N;
    int base = (blockIdx.x * 256 + threadIdx.x) * 4;
    if (base + 3 < E) {
        int4 t = *(const int4*)(ei + E + base);
        atomicAdd(&d[t.x], 1); atomicAdd(&d[t.y], 1);
        atomicAdd(&d[t.z], 1); atomicAdd(&d[t.w], 1);
    } else {
        for (int e = base; e < E; ++e) atomicAdd(&d[ei[E + e]], 1);
    }
}

__global__ __launch_bounds__(256) void zero_kernel(int* __restrict__ p, int n) {
    int i = blockIdx.x * 256 + threadIdx.x;
    if (i < n) p[i] = 0;
}

__global__ __launch_bounds__(256) void scan_partial(const int* __restrict__ deg8, int n, int N,
                                                    int* __restrict__ partial) {
    __shared__ int red[256];
    int b = blockIdx.x, t = threadIdx.x;
    int base = b * 1024 + t * 4;
    int s = 0;
#pragma unroll
    for (int jj = 0; jj < 4; ++jj) {
        int i = base + jj;
        if (i < n) {
#pragma unroll
            for (int j = 0; j < 8; ++j) s += deg8[j * N + i];
        }
    }
    red[t] = s;
    __syncthreads();
    for (int off = 128; off > 0; off >>= 1) {
        if (t < off) red[t] += red[t + off];
        __syncthreads();
    }
    if (t == 0) partial[b] = red[0];
}

__global__ __launch_bounds__(64) void scan_top(int* __restrict__ partial, int nb,
                                               int* __restrict__ offs, int n) {
    int t = threadIdx.x;
    int v = (t < nb) ? partial[t] : 0;
    int incl = v;
    for (int off = 1; off < 64; off <<= 1) {
        int o = __shfl_up(incl, off);
        if (t >= off) incl += o;
    }
    if (t < nb) partial[t] = incl - v;
    if (t == 63) offs[n] = incl;  // == E
}

__global__ __launch_bounds__(256) void scan_apply(const int* __restrict__ deg8, int n, int N,
                                                  const int* __restrict__ partial,
                                                  int* __restrict__ offs, int* __restrict__ cursorc,
                                                  float* __restrict__ dinv) {
    __shared__ int ts[256];
    int b = blockIdx.x, t = threadIdx.x;
    int base = b * 1024 + t * 4;
    int d[4][8], tot[4]; int s = 0;
#pragma unroll
    for (int jj = 0; jj < 4; ++jj) {
        int i = base + jj;
        tot[jj] = 0;
#pragma unroll
        for (int j = 0; j < 8; ++j) {
            d[jj][j] = (i < n) ? deg8[j * N + i] : 0;
            tot[jj] += d[jj][j];
        }
        s += tot[jj];
    }
    ts[t] = s;
    __syncthreads();
    int val = s;
    for (int off = 1; off < 256; off <<= 1) {
        int add = (t >= off) ? ts[t - off] : 0;
        __syncthreads();
        val += add; ts[t] = val;
        __syncthreads();
    }
    int run = val - s + partial[b];
#pragma unroll
    for (int jj = 0; jj < 4; ++jj) {
        int i = base + jj;
        if (i < n) {
            offs[i] = run;
            dinv[i] = rsqrtf((float)(tot[jj] + 1));
            int sub = run;
#pragma unroll
            for (int j = 0; j < 8; ++j) { cursorc[j * N + i] = sub; sub += d[jj][j]; }
        }
        run += tot[jj];
    }
}

__global__ __launch_bounds__(256) void bucket_kernel(const int* __restrict__ ei, int E,
                                                     int* __restrict__ cursorc,
                                                     int* __restrict__ srcs, int N) {
    int j = blockIdx.x & 7;
    int* cur = cursorc + j * N;
    int base = (blockIdx.x * 256 + threadIdx.x) * 4;
    if (base + 3 < E) {
        int4 r = *(const int4*)(ei + base);
        int4 c = *(const int4*)(ei + E + base);
        srcs[atomicAdd(&cur[c.x], 1)] = r.x;
        srcs[atomicAdd(&cur[c.y], 1)] = r.y;
        srcs[atomicAdd(&cur[c.z], 1)] = r.z;
        srcs[atomicAdd(&cur[c.w], 1)] = r.w;
    } else {
        for (int e = base; e < E; ++e)
            srcs[atomicAdd(&cur[ei[E + e]], 1)] = ei[e];
    }
}

__global__ void scale_kernel(const float* __restrict__ x, const float* __restrict__ dinv,
                             uint* __restrict__ z, int n, int nScaleBlocks,
                             const float* __restrict__ W, ushort* __restrict__ Wbf) {
    if (blockIdx.x < (uint)nScaleBlocks) {
        int idx = blockIdx.x * 256 + threadIdx.x;
        int total = n * (D / 2);
        if (idx >= total) return;
        int node = idx >> 6;
        float2 v = ((const float2*)x)[idx];
        float s = dinv[node];
        z[idx] = f2_to_bf2(v.x * s, v.y * s);
    } else {
        int i = (blockIdx.x - nScaleBlocks) * 256 + threadIdx.x;
        if (i < D * D) {
            uint u = __float_as_uint(W[i]);
            u += 0x7fffu + ((u >> 16) & 1u);
            Wbf[i] = (ushort)(u >> 16);
        }
    }
}

__global__ __launch_bounds__(256) void prop_kernel(const uint* __restrict__ zin,
                                                   uint* __restrict__ zout,
                                                   const int* __restrict__ offs,
                                                   const int* __restrict__ srcs,
                                                   const float* __restrict__ dinv,
                                                   int mode, int n) {
    int wv = threadIdx.x >> 6, lane = threadIdx.x & 63;
    int c = blockIdx.x * 4 + wv;
    if (c >= n) return;
    prop_phase(zin, zout, offs, srcs, dinv, mode, c + 1, c, 1 << 30, lane);
}

#define GN 64
__global__ __launch_bounds__(256) void gemm_mfma(const uint4* __restrict__ x2,
                                                 const uint4* __restrict__ Wbf,
                                                 const float* __restrict__ bias,
                                                 float* __restrict__ out, int n) {
    __shared__ __align__(16) ushort xs[GN][136];
    __shared__ __align__(16) ushort ws[D][136];
    int t = threadIdx.x;
    int n0 = blockIdx.x * GN;
    for (int i = t; i < D * 16; i += 256) {
        int row = i >> 4, c8 = i & 15;
        uint4 v = Wbf[i];
        *(uint4*)&ws[row][c8 * 8] = v;
    }
    for (int i = t; i < GN * 16; i += 256) {
        int row = i >> 4, c8 = i & 15;
        int node = n0 + row;
        uint4 v = (node < n) ? x2[(size_t)node * 16 + c8] : make_uint4(0u, 0u, 0u, 0u);
        *(uint4*)&xs[row][c8 * 8] = v;
    }
    __syncthreads();

    int w = t >> 6, lane = t & 63;
    int m0 = w * 16;
    int mrow = lane & 15, quad = lane >> 4;

    bf16x8 a[4];
#pragma unroll
    for (int q = 0; q < 4; ++q)
        a[q] = *(const bf16x8*)&xs[m0 + mrow][q * 32 + quad * 8];

    f32x4 acc[8];
#pragma unroll
    for (int ht = 0; ht < 8; ++ht) {
        acc[ht] = (f32x4){0.f, 0.f, 0.f, 0.f};
#pragma unroll
        for (int q = 0; q < 4; ++q) {
            bf16x8 bfr = *(const bf16x8*)&ws[ht * 16 + mrow][q * 32 + quad * 8];
            acc[ht] = __builtin_amdgcn_mfma_f32_16x16x32_bf16(a[q], bfr, acc[ht], 0, 0, 0);
        }
    }

#pragma unroll
    for (int ht = 0; ht < 8; ++ht) {
        int h = ht * 16 + mrow;
        float bv = bias[h];
#pragma unroll
        for (int reg = 0; reg < 4; ++reg) {
            int node = n0 + m0 + quad * 4 + reg;
            if (node < n)
                out[(size_t)node * D + h] = fmaxf(acc[ht][reg] + bv, 0.f);
        }
    }
}

extern "C" void kernel_launch(void* const* d_in, const int* in_sizes, int n_in,
                              void* d_out, int out_size, void* d_ws, size_t ws_size,
                              hipStream_t stream) {
    const float* x  = (const float*)d_in[0];
    const int*   ei = (const int*)d_in[1];
    const float* W  = (const float*)d_in[2];
    const float* bias = (const float*)d_in[3];
    float* out = (float*)d_out;
    int N = in_sizes[0] / D;   // 50000
    int E = in_sizes[1] / 2;   // 600000

    char* p = (char*)d_ws;
    auto alloc = [&](size_t bytes) -> void* {
        void* r = p; p += (bytes + 511) & ~(size_t)511; return r;
    };
    int*    deg8    = (int*)alloc((size_t)8 * N * 4);
    int*    offs    = (int*)alloc(((size_t)N + 1) * 4);
    int*    cursorc = (int*)alloc((size_t)8 * N * 4);
    int*    srcs    = (int*)alloc((size_t)E * 4);
    float*  dinv    = (float*)alloc((size_t)N * 4);
    int*    partial = (int*)alloc(64 * 4);
    uint*   zA      = (uint*)alloc((size_t)N * (D / 2) * 4);  // bf16-packed
    uint*   zB      = (uint*)alloc((size_t)N * (D / 2) * 4);
    ushort* Wbf     = (ushort*)alloc((size_t)D * D * 2);

    void* args[] = {
        (void*)&x, (void*)&ei, (void*)&W, (void*)&bias, (void*)&out,
        (void*)&N, (void*)&E,
        (void*)&deg8, (void*)&offs, (void*)&cursorc, (void*)&srcs,
        (void*)&dinv, (void*)&partial, (void*)&zA, (void*)&zB, (void*)&Wbf
    };
    hipError_t err = hipLaunchCooperativeKernel((const void*)mega_kernel,
                                                dim3(NBLK), dim3(NTHR), args, 0, stream);
    if (err != hipSuccess) {
        // deterministic fallback: proven R4 multi-kernel path
        int nb = (N + 1023) / 1024;
        int ebBlocks = (E + 1023) / 1024;
        int nScaleBlocks = (N * (D / 2) + 255) / 256;
        int nWBlocks = (D * D + 255) / 256;
        zero_kernel<<<(8 * N + 255) / 256, 256, 0, stream>>>(deg8, 8 * N);
        count_kernel<<<ebBlocks, 256, 0, stream>>>(ei, E, deg8, N);
        scan_partial<<<nb, 256, 0, stream>>>(deg8, N, N, partial);
        scan_top<<<1, 64, 0, stream>>>(partial, nb, offs, N);
        scan_apply<<<nb, 256, 0, stream>>>(deg8, N, N, partial, offs, cursorc, dinv);
        bucket_kernel<<<ebBlocks, 256, 0, stream>>>(ei, E, cursorc, srcs, N);
        scale_kernel<<<nScaleBlocks + nWBlocks, 256, 0, stream>>>(x, dinv, zA, N, nScaleBlocks, W, Wbf);
        prop_kernel<<<(N + 3) / 4, 256, 0, stream>>>(zA, zB, offs, srcs, dinv, 0, N);
        prop_kernel<<<(N + 3) / 4, 256, 0, stream>>>(zB, zA, offs, srcs, dinv, 1, N);
        gemm_mfma<<<(N + GN - 1) / GN, 256, 0, stream>>>((const uint4*)zA, (const uint4*)Wbf, bias, out, N);
    }
}

// Round 7
// 231.042 us; speedup vs baseline: 6.3394x; 6.3394x over previous
//
#include <hip/hip_runtime.h>

#define D 128
typedef unsigned int uint;
typedef unsigned short ushort;
typedef __attribute__((ext_vector_type(8))) short bf16x8;
typedef __attribute__((ext_vector_type(4))) float f32x4;

// ---- bf16x2 pack/unpack (packed uint: low16 = even dim, high16 = odd dim) ----
__device__ __forceinline__ float2 bf2_to_f2(uint v) {
    union { uint u; float f; } a, b;
    a.u = v << 16;
    b.u = v & 0xffff0000u;
    return make_float2(a.f, b.f);
}
__device__ __forceinline__ uint f2_to_bf2(float x, float y) {
    uint xu = __float_as_uint(x), yu = __float_as_uint(y);
    xu += 0x7fffu + ((xu >> 16) & 1u);   // round-to-nearest-even
    yu += 0x7fffu + ((yu >> 16) & 1u);
    return (xu >> 16) | (yu & 0xffff0000u);
}

// ---- K1: fused count (in-degree) + x->bf16 cast + W->bf16 cast ----
// block roles: [0,cntB) count | [cntB,cntB+xB) xcast | [cntB+xB, ...) wcast
__global__ __launch_bounds__(256) void count_cast_kernel(
        const int* __restrict__ ei, int E, int* __restrict__ deg,
        const float* __restrict__ x, uint2* __restrict__ zX, int n,
        const float* __restrict__ W, uint* __restrict__ Wbf,
        int cntB, int xB) {
    int b = blockIdx.x, t = threadIdx.x;
    if (b < cntB) {
        int base = (b * 256 + t) * 4;
        if (base + 3 < E) {
            int4 c4 = *(const int4*)(ei + E + base);
            atomicAdd(&deg[c4.x], 1); atomicAdd(&deg[c4.y], 1);
            atomicAdd(&deg[c4.z], 1); atomicAdd(&deg[c4.w], 1);
        } else {
            for (int e = base; e < E; ++e) atomicAdd(&deg[ei[E + e]], 1);
        }
    } else if (b < cntB + xB) {
        int idx = (b - cntB) * 256 + t;          // one float4 -> uint2 per thread
        if (idx < n * 32) {
            float4 v = ((const float4*)x)[idx];
            uint2 o;
            o.x = f2_to_bf2(v.x, v.y);
            o.y = f2_to_bf2(v.z, v.w);
            zX[idx] = o;
        }
    } else {
        int i = (b - cntB - xB) * 256 + t;       // one float2 -> uint per thread
        if (i < (D * D) / 2) {
            float2 wv = ((const float2*)W)[i];
            Wbf[i] = f2_to_bf2(wv.x, wv.y);
        }
    }
}

// ---- K2: per-1024-node chunk sums ----
__global__ __launch_bounds__(256) void scan_partial(const int* __restrict__ deg, int n,
                                                    int* __restrict__ partial) {
    __shared__ int red[256];
    int b = blockIdx.x, t = threadIdx.x;
    int base = b * 1024 + t * 4;
    int s = 0;
#pragma unroll
    for (int j = 0; j < 4; ++j) { int i = base + j; if (i < n) s += deg[i]; }
    red[t] = s;
    __syncthreads();
    for (int off = 128; off > 0; off >>= 1) {
        if (t < off) red[t] += red[t + off];
        __syncthreads();
    }
    if (t == 0) partial[b] = red[0];
}

// ---- K3: apply — every block redundantly wave-scans the <=64 partials (no 3rd kernel) ----
__global__ __launch_bounds__(256) void scan_apply(const int* __restrict__ deg, int n, int nb,
                                                  const int* __restrict__ partial,
                                                  int* __restrict__ offs, int* __restrict__ cursor,
                                                  float* __restrict__ dinv, int E) {
    __shared__ int ts[256];
    __shared__ int chunk_exc;
    int b = blockIdx.x, t = threadIdx.x;
    if (t < 64) {                      // wave 0: exclusive prefix of chunk b
        int v = (t < nb) ? partial[t] : 0;
        int incl = v;
        for (int off = 1; off < 64; off <<= 1) {
            int o = __shfl_up(incl, off);
            if (t >= off) incl += o;
        }
        if (t == b) chunk_exc = incl - v;
        if (b == 0 && t == 0) offs[n] = E;
    }
    int base = b * 1024 + t * 4;
    int v[4]; int s = 0;
#pragma unroll
    for (int j = 0; j < 4; ++j) { int i = base + j; v[j] = (i < n) ? deg[i] : 0; s += v[j]; }
    ts[t] = s;
    __syncthreads();
    int val = s;
    for (int off = 1; off < 256; off <<= 1) {
        int add = (t >= off) ? ts[t - off] : 0;
        __syncthreads();
        val += add; ts[t] = val;
        __syncthreads();
    }
    int run = val - s + chunk_exc;
#pragma unroll
    for (int j = 0; j < 4; ++j) {
        int i = base + j;
        if (i < n) {
            offs[i] = run; cursor[i] = run;
            dinv[i] = rsqrtf((float)(v[j] + 1));   // +1 self-loop
        }
        run += v[j];
    }
}

// ---- K4: counting-sort edges by target ----
__global__ __launch_bounds__(256) void bucket_kernel(const int* __restrict__ ei, int E,
                                                     int* __restrict__ cursor,
                                                     int* __restrict__ srcs) {
    int base = (blockIdx.x * 256 + threadIdx.x) * 4;
    if (base + 3 < E) {
        int4 r = *(const int4*)(ei + base);
        int4 c = *(const int4*)(ei + E + base);
        srcs[atomicAdd(&cursor[c.x], 1)] = r.x;
        srcs[atomicAdd(&cursor[c.y], 1)] = r.y;
        srcs[atomicAdd(&cursor[c.z], 1)] = r.z;
        srcs[atomicAdd(&cursor[c.w], 1)] = r.w;
    } else {
        for (int e = base; e < E; ++e)
            srcs[atomicAdd(&cursor[ei[E + e]], 1)] = ei[e];
    }
}

// ---- K5: hop 1 with fused input scaling:
//      z1[c] = dinv[c]^2 * ( dinv[c]*xbf[c] + sum_r dinv[r]*xbf[r] ) ----
__global__ __launch_bounds__(256) void prop1_kernel(const uint* __restrict__ zin,
                                                    uint* __restrict__ zout,
                                                    const int* __restrict__ offs,
                                                    const int* __restrict__ srcs,
                                                    const float* __restrict__ dinv,
                                                    int n) {
    int wv = threadIdx.x >> 6, lane = threadIdx.x & 63;
    int c = blockIdx.x * 4 + wv;
    if (c >= n) return;
    int beg = offs[c], end = offs[c + 1];
    size_t selfoff = (size_t)c * 64 + lane;
    float dc = dinv[c];
    float2 sf = bf2_to_f2(zin[selfoff]);
    float2 acc = make_float2(sf.x * dc, sf.y * dc);   // self-loop: weight dinv[c]
    int k = beg;
    for (; k + 7 < end; k += 8) {                     // 8 rows in flight
        int r0 = srcs[k],     r1 = srcs[k + 1], r2 = srcs[k + 2], r3 = srcs[k + 3];
        int r4 = srcs[k + 4], r5 = srcs[k + 5], r6 = srcs[k + 6], r7 = srcs[k + 7];
        uint v0 = zin[(size_t)r0 * 64 + lane], v1 = zin[(size_t)r1 * 64 + lane];
        uint v2 = zin[(size_t)r2 * 64 + lane], v3 = zin[(size_t)r3 * 64 + lane];
        uint v4 = zin[(size_t)r4 * 64 + lane], v5 = zin[(size_t)r5 * 64 + lane];
        uint v6 = zin[(size_t)r6 * 64 + lane], v7 = zin[(size_t)r7 * 64 + lane];
        float d0 = dinv[r0], d1 = dinv[r1], d2 = dinv[r2], d3 = dinv[r3];
        float d4 = dinv[r4], d5 = dinv[r5], d6 = dinv[r6], d7 = dinv[r7];
        float2 f0 = bf2_to_f2(v0), f1 = bf2_to_f2(v1), f2 = bf2_to_f2(v2), f3 = bf2_to_f2(v3);
        float2 f4 = bf2_to_f2(v4), f5 = bf2_to_f2(v5), f6 = bf2_to_f2(v6), f7 = bf2_to_f2(v7);
        acc.x += (fmaf(d0, f0.x, d1 * f1.x) + fmaf(d2, f2.x, d3 * f3.x))
               + (fmaf(d4, f4.x, d5 * f5.x) + fmaf(d6, f6.x, d7 * f7.x));
        acc.y += (fmaf(d0, f0.y, d1 * f1.y) + fmaf(d2, f2.y, d3 * f3.y))
               + (fmaf(d4, f4.y, d5 * f5.y) + fmaf(d6, f6.y, d7 * f7.y));
    }
    for (; k < end; ++k) {
        int r = srcs[k];
        float dr = dinv[r];
        float2 f = bf2_to_f2(zin[(size_t)r * 64 + lane]);
        acc.x = fmaf(dr, f.x, acc.x);
        acc.y = fmaf(dr, f.y, acc.y);
    }
    float sc = dc * dc;
    zout[selfoff] = f2_to_bf2(acc.x * sc, acc.y * sc);
}

// ---- K6: hop 2: z2[c] = dinv[c] * ( z1[c] + sum_r z1[r] ) ----
__global__ __launch_bounds__(256) void prop2_kernel(const uint* __restrict__ zin,
                                                    uint* __restrict__ zout,
                                                    const int* __restrict__ offs,
                                                    const int* __restrict__ srcs,
                                                    const float* __restrict__ dinv,
                                                    int n) {
    int wv = threadIdx.x >> 6, lane = threadIdx.x & 63;
    int c = blockIdx.x * 4 + wv;
    if (c >= n) return;
    int beg = offs[c], end = offs[c + 1];
    size_t selfoff = (size_t)c * 64 + lane;
    float2 acc = bf2_to_f2(zin[selfoff]);
    int k = beg;
    for (; k + 7 < end; k += 8) {
        uint v0 = zin[(size_t)srcs[k]     * 64 + lane], v1 = zin[(size_t)srcs[k + 1] * 64 + lane];
        uint v2 = zin[(size_t)srcs[k + 2] * 64 + lane], v3 = zin[(size_t)srcs[k + 3] * 64 + lane];
        uint v4 = zin[(size_t)srcs[k + 4] * 64 + lane], v5 = zin[(size_t)srcs[k + 5] * 64 + lane];
        uint v6 = zin[(size_t)srcs[k + 6] * 64 + lane], v7 = zin[(size_t)srcs[k + 7] * 64 + lane];
        float2 f0 = bf2_to_f2(v0), f1 = bf2_to_f2(v1), f2 = bf2_to_f2(v2), f3 = bf2_to_f2(v3);
        float2 f4 = bf2_to_f2(v4), f5 = bf2_to_f2(v5), f6 = bf2_to_f2(v6), f7 = bf2_to_f2(v7);
        acc.x += ((f0.x + f1.x) + (f2.x + f3.x)) + ((f4.x + f5.x) + (f6.x + f7.x));
        acc.y += ((f0.y + f1.y) + (f2.y + f3.y)) + ((f4.y + f5.y) + (f6.y + f7.y));
    }
    for (; k < end; ++k) {
        float2 f = bf2_to_f2(zin[(size_t)srcs[k] * 64 + lane]);
        acc.x += f.x; acc.y += f.y;
    }
    float s = dinv[c];
    zout[selfoff] = f2_to_bf2(acc.x * s, acc.y * s);
}

// ---- K7: out = relu(z2 @ W^T + b) via MFMA bf16; 64 nodes/block ----
#define GN 64
__global__ __launch_bounds__(256) void gemm_mfma(const uint4* __restrict__ x2,
                                                 const uint4* __restrict__ Wbf,
                                                 const float* __restrict__ bias,
                                                 float* __restrict__ out, int n) {
    __shared__ __align__(16) ushort xs[GN][136];   // +8 pad: conflict-free b128 frag reads
    __shared__ __align__(16) ushort ws[D][136];
    int t = threadIdx.x;
    int n0 = blockIdx.x * GN;
    for (int i = t; i < D * 16; i += 256) {
        int row = i >> 4, c8 = i & 15;
        uint4 v = Wbf[i];
        *(uint4*)&ws[row][c8 * 8] = v;
    }
    for (int i = t; i < GN * 16; i += 256) {
        int row = i >> 4, c8 = i & 15;
        int node = n0 + row;
        uint4 v = (node < n) ? x2[(size_t)node * 16 + c8] : make_uint4(0u, 0u, 0u, 0u);
        *(uint4*)&xs[row][c8 * 8] = v;
    }
    __syncthreads();

    int w = t >> 6, lane = t & 63;
    int m0 = w * 16;
    int mrow = lane & 15, quad = lane >> 4;

    bf16x8 a[4];
#pragma unroll
    for (int q = 0; q < 4; ++q)
        a[q] = *(const bf16x8*)&xs[m0 + mrow][q * 32 + quad * 8];   // A[m=lane&15][k]

    f32x4 acc[8];
#pragma unroll
    for (int ht = 0; ht < 8; ++ht) {
        acc[ht] = (f32x4){0.f, 0.f, 0.f, 0.f};
#pragma unroll
        for (int q = 0; q < 4; ++q) {
            bf16x8 bfr = *(const bf16x8*)&ws[ht * 16 + mrow][q * 32 + quad * 8];  // B[k][n]=W[h=n][d=k]
            acc[ht] = __builtin_amdgcn_mfma_f32_16x16x32_bf16(a[q], bfr, acc[ht], 0, 0, 0);
        }
    }

#pragma unroll
    for (int ht = 0; ht < 8; ++ht) {
        int h = ht * 16 + mrow;
        float bv = bias[h];
#pragma unroll
        for (int reg = 0; reg < 4; ++reg) {
            int node = n0 + m0 + quad * 4 + reg;   // C/D: col=lane&15, row=quad*4+reg
            if (node < n)
                out[(size_t)node * D + h] = fmaxf(acc[ht][reg] + bv, 0.f);
        }
    }
}

extern "C" void kernel_launch(void* const* d_in, const int* in_sizes, int n_in,
                              void* d_out, int out_size, void* d_ws, size_t ws_size,
                              hipStream_t stream) {
    const float* x  = (const float*)d_in[0];
    const int*   ei = (const int*)d_in[1];
    const float* W  = (const float*)d_in[2];
    const float* bias = (const float*)d_in[3];
    float* out = (float*)d_out;
    int N = in_sizes[0] / D;   // 50000
    int E = in_sizes[1] / 2;   // 600000

    char* p = (char*)d_ws;
    auto alloc = [&](size_t bytes) -> void* {
        void* r = p; p += (bytes + 511) & ~(size_t)511; return r;
    };
    int*    deg     = (int*)alloc((size_t)N * 4);
    int*    offs    = (int*)alloc(((size_t)N + 1) * 4);
    int*    cursor  = (int*)alloc((size_t)N * 4);
    int*    srcs    = (int*)alloc((size_t)E * 4);
    float*  dinv    = (float*)alloc((size_t)N * 4);
    int*    partial = (int*)alloc(64 * 4);
    uint*   zX      = (uint*)alloc((size_t)N * 64 * 4);   // bf16(x), unscaled
    uint*   zB      = (uint*)alloc((size_t)N * 64 * 4);   // z1
    uint*   zA      = (uint*)alloc((size_t)N * 64 * 4);   // z2
    uint*   Wbf     = (uint*)alloc((size_t)(D * D / 2) * 4);

    int nb   = (N + 1023) / 1024;          // 49 (<= 64 for in-block top-scan)
    int cntB = (E + 1023) / 1024;          // 586
    int xB   = (N * 32 + 255) / 256;       // 6250
    int wB   = ((D * D / 2) + 255) / 256;  // 32

    hipMemsetAsync(deg, 0, (size_t)N * 4, stream);
    count_cast_kernel<<<cntB + xB + wB, 256, 0, stream>>>(ei, E, deg, x, (uint2*)zX, N,
                                                          W, Wbf, cntB, xB);
    scan_partial<<<nb, 256, 0, stream>>>(deg, N, partial);
    scan_apply<<<nb, 256, 0, stream>>>(deg, N, nb, partial, offs, cursor, dinv, E);
    bucket_kernel<<<cntB, 256, 0, stream>>>(ei, E, cursor, srcs);
    prop1_kernel<<<(N + 3) / 4, 256, 0, stream>>>(zX, zB, offs, srcs, dinv, N);
    prop2_kernel<<<(N + 3) / 4, 256, 0, stream>>>(zB, zA, offs, srcs, dinv, N);
    gemm_mfma<<<(N + GN - 1) / GN, 256, 0, stream>>>((const uint4*)zA, (const uint4*)Wbf, bias, out, N);
}